// Round 17
// baseline (91.755 us; speedup 1.0000x reference)
//
#include <hip/hip_runtime.h>
#include <math.h>

// Soft-DTW (DILATE, alpha=1, gamma=0.01), B=64, N=512, F=1, n=511.
// Hard-min DP (exact-to-threshold since R8). One block/batch; 256 threads =
// 4 waves; thread T owns DP rows {2T, 2T+1}. KCH=32 diagonals per handoff.
// R17: ZERO LDS ops inside the step. R14's "register windows" were never
// register-resident (VGPR_Count=72 vs ~145 needed; LLVM remats LDS loads at
// each use) -> ~12 hidden ds_read/step/CU on the shared LDS pipe = the
// fitted 64 cy/step. Fix: all per-step values are computed or conveyed:
//   dx: conveyor pair (XB,XA)=(dx[m],dx[m+1]); adjacent lanes differ by 2 in
//       m, so one dpp wave_shr1 per value advances 2 steps; lane-0 injection
//       via v_readlane from WV (ONE lane-indexed ds_read per chunk) riding
//       the DPP old operand.
//   mailbox: MV = Mbx[w][32c+lane] (ONE ds_read per chunk); per step
//       readlane(MV, K+1) -> DPP old operand of the row-recurrence shift.
// Cells (diag d, rows 2T lo / 2T+1 hi):
//   sh1   = dpp_shr1(r1_hi) with lane0 := M(d-1)
//   nv_lo = min3(SH2, sh1, r1_lo)     + (dy_lo - dx[d-2T-1])^2
//   nv_hi = min3(r2_lo, r1_lo, r1_hi) + (dy_hi - dx[d-2T-2])^2
// No validity masking (invalid cells hold ~INF; ulp(1e9)=64 >> u^2).

#define INF_F 1000000000.0f

// whole-wave shift right by 1; lane0 receives `oldv` (bound_ctrl=0 keeps old)
__device__ __forceinline__ float dpp_shr1_inj(float x, float oldv){
  int r = __builtin_amdgcn_update_dpp(__float_as_int(oldv), __float_as_int(x),
                                      0x138 /*WAVE_SHR1*/, 0xf, 0xf, false);
  return __int_as_float(r);
}
__device__ __forceinline__ float min3f(float a, float b, float c){
  float d;
  asm("v_min3_f32 %0, %1, %2, %3" : "=v"(d) : "v"(a), "v"(b), "v"(c));
  return d;
}
__device__ __forceinline__ float rdlane(float v, int k){
  return __int_as_float(__builtin_amdgcn_readlane(__float_as_int(v), k));
}
#define PINF(v) asm volatile("" : "+v"(v))

// Two diagonals (steps KA=even, KB=KA+1). Conveyor invariant at pair start:
//   XB = dx[m], XA = dx[m+1], m = 32c + KA - 2T - 2.
#define STEP2D(KA, KB) { \
  /* step KA (diag d): hi uses XB, lo uses XA */ \
  float sh1a = dpp_shr1_inj(r1_hi, rdlane(MV, (KA)+1)); \
  float uLa = dy_lo - XA; \
  float uHa = dy_hi - XB; \
  float nloA = fmaf(uLa, uLa, min3f(SH2, sh1a, r1_lo)); \
  float nhiA = fmaf(uHa, uHa, min3f(r2_lo, r1_lo, r1_hi)); \
  pb##KA = nhiA; \
  if ((KA) == 28) { if (cc == 31) ans = nhiA; } \
  /* conveyor: XC = dx[m+2] (needed by step KB's lo) */ \
  float XC = dpp_shr1_inj(XB, rdlane(WV, (KA))); \
  /* step KB (diag d+1): hi uses XA, lo uses XC */ \
  float sh1b = dpp_shr1_inj(nhiA, rdlane(MV, (KA)+2)); \
  float uLb = dy_lo - XC; \
  float uHb = dy_hi - XA; \
  float nloB = fmaf(uLb, uLb, min3f(sh1a, sh1b, nloA)); \
  float nhiB = fmaf(uHb, uHb, min3f(r1_lo, nloA, nhiA)); \
  pb##KB = nhiB; \
  /* advance conveyor to m+2: XB'=XC, XA'=dx[m+3] */ \
  XB = XC; \
  XA = dpp_shr1_inj(XA, rdlane(WV, (KB))); \
  /* state: r2_lo = lo@d, r1 = diag d+1, SH2 = neighbor hi @ d */ \
  SH2 = sh1b; r2_lo = nloA; r1_lo = nloB; r1_hi = nhiB; }

__global__ __launch_bounds__(256, 1)
void sdtw_kernel(const float* __restrict__ input,
                 const float* __restrict__ target,
                 float* __restrict__ out) {
  const int b = blockIdx.x;
  const int t = threadIdx.x;          // T = 0..255; rows 2T, 2T+1
  const int w = t >> 6;               // wave 0..3
  const int lane = t & 63;

  __shared__ __align__(8) float dxe[1576];     // dx[j] at dxe[514+j]; zero pad
  __shared__ __align__(16) float Mbx[4][1060]; // Mbx[w][d] = boundary diag d
  __shared__ int flagz[4];

  const float* __restrict__ inp = input + b * 512;
  const float* __restrict__ tgt = target + b * 512;

  for (int idx = t; idx < 1576; idx += 256) {
    float v = 0.0f;
    if (idx >= 514 && idx <= 1024) v = inp[idx - 513] - inp[idx - 514];
    dxe[idx] = v;
  }
  for (int k2 = t; k2 < 4 * 1060; k2 += 256) (&Mbx[0][0])[k2] = INF_F;
  if (t < 4) flagz[t] = 0;

  // dy for the two owned rows
  float dy_lo = (t >= 1) ? (tgt[2*t] - tgt[2*t - 1]) : 0.0f;  // row 2T
  float dy_hi = tgt[2*t + 1] - tgt[2*t];                      // row 2T+1

  // state at d=2: diag-1 all INF; diag-0: R[0][0]=0 in lane0's r2_lo
  float r1_lo = INF_F, r1_hi = INF_F;
  float r2_lo = (t == 0) ? 0.0f : INF_F;
  float SH2   = INF_F;                // neighbor hi @ diag 0

  float pb0,  pb1,  pb2,  pb3,  pb4,  pb5,  pb6,  pb7;
  float pb8,  pb9,  pb10, pb11, pb12, pb13, pb14, pb15;
  float pb16, pb17, pb18, pb19, pb20, pb21, pb22, pb23;
  float pb24, pb25, pb26, pb27, pb28, pb29, pb30, pb31;

  float ans = INF_F;
  const float2* dxe2 = (const float2*)dxe;

  __syncthreads();                    // staging visible; only barrier

  // conveyor init for c=0, KA=0: m = -2T-2 -> XB=dx[-2T], XA=dx[1-2T]
  float2 xx = dxe2[257 - t];
  float XB = xx.x, XA = xx.y;
  PINF(XB); PINF(XA);

#pragma unroll 1
  for (int c = 0; c < 32; ++c) {
    const int cc = c;
    // WV[lane] = dx[32c + lane - 128w]  (conveyor injections, no dep on pred)
    float WV = dxe[514 + 32 * cc + lane - 128 * w];
    if (w > 0) {
      while (__hip_atomic_load(&flagz[w - 1], __ATOMIC_ACQUIRE,
                               __HIP_MEMORY_SCOPE_WORKGROUP) <= cc) {}
    }
    // MV[lane] = M(32c + lane)  (mailbox window, one read per chunk)
    float MV = Mbx[w][32 * cc + lane];
    PINF(WV); PINF(MV);
    asm volatile("" ::: "memory");

    STEP2D(0, 1)   STEP2D(2, 3)   STEP2D(4, 5)   STEP2D(6, 7)
    STEP2D(8, 9)   STEP2D(10, 11) STEP2D(12, 13) STEP2D(14, 15)
    STEP2D(16, 17) STEP2D(18, 19) STEP2D(20, 21) STEP2D(22, 23)
    STEP2D(24, 25) STEP2D(26, 27) STEP2D(28, 29) STEP2D(30, 31)

    if (w < 3) {
      if (lane == 63) {
        float2* Pd = (float2*)&Mbx[w + 1][32 * cc + 2];
        Pd[0]  = make_float2(pb0,  pb1);  Pd[1]  = make_float2(pb2,  pb3);
        Pd[2]  = make_float2(pb4,  pb5);  Pd[3]  = make_float2(pb6,  pb7);
        Pd[4]  = make_float2(pb8,  pb9);  Pd[5]  = make_float2(pb10, pb11);
        Pd[6]  = make_float2(pb12, pb13); Pd[7]  = make_float2(pb14, pb15);
        Pd[8]  = make_float2(pb16, pb17); Pd[9]  = make_float2(pb18, pb19);
        Pd[10] = make_float2(pb20, pb21); Pd[11] = make_float2(pb22, pb23);
        Pd[12] = make_float2(pb24, pb25); Pd[13] = make_float2(pb26, pb27);
        Pd[14] = make_float2(pb28, pb29); Pd[15] = make_float2(pb30, pb31);
      }
      __hip_atomic_store(&flagz[w], cc + 1, __ATOMIC_RELEASE,
                         __HIP_MEMORY_SCOPE_WORKGROUP);
    }
  }

  if (w == 3 && lane == 63) {
    atomicAdd(out, ans * (1.0f / 64.0f));
  }
}

extern "C" void kernel_launch(void* const* d_in, const int* in_sizes, int n_in,
                              void* d_out, int out_size, void* d_ws, size_t ws_size,
                              hipStream_t stream) {
  const float* input  = (const float*)d_in[0];
  const float* target = (const float*)d_in[1];
  float* out = (float*)d_out;

  hipMemsetAsync(out, 0, sizeof(float), stream);
  sdtw_kernel<<<64, 256, 0, stream>>>(input, target, out);
}

// Round 18
// 85.821 us; speedup vs baseline: 1.0692x; 1.0692x over previous
//
#include <hip/hip_runtime.h>
#include <math.h>

// Soft-DTW (DILATE, alpha=1, gamma=0.01), B=64, N=512, F=1, n=511.
// Hard-min DP (exact-to-threshold since R8). One block/batch; 256 threads =
// 4 waves; thread t owns DP rows {2t, 2t+1}. KCH=32 diagonals per handoff.
// R18 = R16 + s_sleep(1) in the spin-poll loop. Rationale: s=64cy/step is
// invariant across instr count / waves-per-SIMD / LDS-vs-conveyor; the one
// constant is 3 waves continuously spin-polling LDS flags (no backoff),
// congesting the CU-shared LDS pipe that the compute wave's per-step reads
// and publishes must traverse. Sleeping pollers cut poll traffic ~8x for
// <=64cy/chunk added discovery latency.
//   sh1   = dpp_shr1(r1_hi) with lane0 := mailbox[d-1]
//   nv_lo = min3(SH2, sh1, r1_lo)     + (dy[2t]   - dx[j_lo-1])^2
//   nv_hi = min3(r2_lo, r1_lo, r1_hi) + (dy[2t+1] - dx[j_hi-1])^2
// No validity masking: invalid cells hold ~INF by construction (ulp(1e9)=64
// absorbs u^2 increments). dx window preloaded per chunk via float2 LDS
// reads, double-buffered. Wave->wave dep via LDS mailbox + acquire/release.

#define INF_F 1000000000.0f

typedef float v4f __attribute__((ext_vector_type(4)));

// whole-wave shift right by 1; lane0 receives `oldv` (bound_ctrl=0 keeps old)
__device__ __forceinline__ float dpp_shr1_inj(float x, float oldv){
  int r = __builtin_amdgcn_update_dpp(__float_as_int(oldv), __float_as_int(x),
                                      0x138 /*WAVE_SHR1*/, 0xf, 0xf, false);
  return __int_as_float(r);
}
__device__ __forceinline__ float min3f(float a, float b, float c){
  float d;
  asm("v_min3_f32 %0, %1, %2, %3" : "=v"(d) : "v"(a), "v"(b), "v"(c));
  return d;
}
#define PINF(v) asm volatile("" : "+v"(v))

// load 34-float window (17 float2, even-aligned) into P##0..P##33
#define LOADW(P, B2) { const float2* _p = dxe2 + (B2); \
  float2 a0=_p[0],a1=_p[1],a2=_p[2],a3=_p[3],a4=_p[4],a5=_p[5],a6=_p[6],a7=_p[7]; \
  float2 a8=_p[8],a9=_p[9],a10=_p[10],a11=_p[11],a12=_p[12],a13=_p[13]; \
  float2 a14=_p[14],a15=_p[15],a16=_p[16]; \
  P##0=a0.x;  P##1=a0.y;  P##2=a1.x;  P##3=a1.y;  P##4=a2.x;  P##5=a2.y; \
  P##6=a3.x;  P##7=a3.y;  P##8=a4.x;  P##9=a4.y;  P##10=a5.x; P##11=a5.y; \
  P##12=a6.x; P##13=a6.y; P##14=a7.x; P##15=a7.y; P##16=a8.x; P##17=a8.y; \
  P##18=a9.x; P##19=a9.y; P##20=a10.x;P##21=a10.y;P##22=a11.x;P##23=a11.y; \
  P##24=a12.x;P##25=a12.y;P##26=a13.x;P##27=a13.y;P##28=a14.x;P##29=a14.y; \
  P##30=a15.x;P##31=a15.y;P##32=a16.x;P##33=a16.y; }

#define PINW(P) { PINF(P##0); PINF(P##1); PINF(P##2); PINF(P##3); PINF(P##4); \
  PINF(P##5); PINF(P##6); PINF(P##7); PINF(P##8); PINF(P##9); PINF(P##10); \
  PINF(P##11); PINF(P##12); PINF(P##13); PINF(P##14); PINF(P##15); PINF(P##16); \
  PINF(P##17); PINF(P##18); PINF(P##19); PINF(P##20); PINF(P##21); PINF(P##22); \
  PINF(P##23); PINF(P##24); PINF(P##25); PINF(P##26); PINF(P##27); PINF(P##28); \
  PINF(P##29); PINF(P##30); PINF(P##31); PINF(P##32); PINF(P##33); }

// One diagonal, two cells. MB = mailbox value at diag d-1 (rides DPP old).
// XLO = dx[j_lo-1] = window[K+1], XHI = dx[j_hi-1] = window[K].
#define STEP2(K, MB, XLO, XHI) { \
  float sh1 = dpp_shr1_inj(r1_hi, (MB)); \
  float uL  = dy_lo - (XLO); \
  float uH  = dy_hi - (XHI); \
  float nv_hi = fmaf(uH, uH, min3f(r2_lo, r1_lo, r1_hi)); \
  float nv_lo = fmaf(uL, uL, min3f(SH2, sh1, r1_lo)); \
  pb##K = nv_hi; \
  if ((K) == 28) { if (cc == 31) ans = nv_hi; } \
  SH2 = sh1; r2_lo = r1_lo; r1_lo = nv_lo; r1_hi = nv_hi; }

#define CHUNK(C, XU, XP) { \
  const int cc = (C); \
  if (w > 0) { \
    while (__hip_atomic_load(&flagz[w-1], __ATOMIC_ACQUIRE, \
                             __HIP_MEMORY_SCOPE_WORKGROUP) <= cc) { \
      __builtin_amdgcn_s_sleep(1); \
    } \
    const v4f* Mr = (const v4f*)&Mbx[w][32*cc]; \
    q0 = Mr[0]; q1 = Mr[1]; q2 = Mr[2]; q3 = Mr[3]; \
    q4 = Mr[4]; q5 = Mr[5]; q6 = Mr[6]; q7 = Mr[7]; \
    m32v = Mbx[w][32*cc+32]; \
    PINF(q0); PINF(q1); PINF(q2); PINF(q3); \
    PINF(q4); PINF(q5); PINF(q6); PINF(q7); PINF(m32v); \
  } \
  PINW(XU); \
  LOADW(XP, 257 + 16*(cc+1) - t); \
  asm volatile("" ::: "memory"); \
  STEP2(0,  q0.y,  XU##1,  XU##0 ) STEP2(1,  q0.z,  XU##2,  XU##1 ) \
  STEP2(2,  q0.w,  XU##3,  XU##2 ) STEP2(3,  q1.x,  XU##4,  XU##3 ) \
  STEP2(4,  q1.y,  XU##5,  XU##4 ) STEP2(5,  q1.z,  XU##6,  XU##5 ) \
  STEP2(6,  q1.w,  XU##7,  XU##6 ) STEP2(7,  q2.x,  XU##8,  XU##7 ) \
  STEP2(8,  q2.y,  XU##9,  XU##8 ) STEP2(9,  q2.z,  XU##10, XU##9 ) \
  STEP2(10, q2.w,  XU##11, XU##10) STEP2(11, q3.x,  XU##12, XU##11) \
  STEP2(12, q3.y,  XU##13, XU##12) STEP2(13, q3.z,  XU##14, XU##13) \
  STEP2(14, q3.w,  XU##15, XU##14) STEP2(15, q4.x,  XU##16, XU##15) \
  STEP2(16, q4.y,  XU##17, XU##16) STEP2(17, q4.z,  XU##18, XU##17) \
  STEP2(18, q4.w,  XU##19, XU##18) STEP2(19, q5.x,  XU##20, XU##19) \
  STEP2(20, q5.y,  XU##21, XU##20) STEP2(21, q5.z,  XU##22, XU##21) \
  STEP2(22, q5.w,  XU##23, XU##22) STEP2(23, q6.x,  XU##24, XU##23) \
  STEP2(24, q6.y,  XU##25, XU##24) STEP2(25, q6.z,  XU##26, XU##25) \
  STEP2(26, q6.w,  XU##27, XU##26) STEP2(27, q7.x,  XU##28, XU##27) \
  STEP2(28, q7.y,  XU##29, XU##28) STEP2(29, q7.z,  XU##30, XU##29) \
  STEP2(30, q7.w,  XU##31, XU##30) STEP2(31, m32v,  XU##32, XU##31) \
  if (w < 3) { \
    if (lane == 63) { \
      float2* Pd = (float2*)&Mbx[w+1][32*cc+2]; \
      Pd[0]  = make_float2(pb0,  pb1);  Pd[1]  = make_float2(pb2,  pb3); \
      Pd[2]  = make_float2(pb4,  pb5);  Pd[3]  = make_float2(pb6,  pb7); \
      Pd[4]  = make_float2(pb8,  pb9);  Pd[5]  = make_float2(pb10, pb11); \
      Pd[6]  = make_float2(pb12, pb13); Pd[7]  = make_float2(pb14, pb15); \
      Pd[8]  = make_float2(pb16, pb17); Pd[9]  = make_float2(pb18, pb19); \
      Pd[10] = make_float2(pb20, pb21); Pd[11] = make_float2(pb22, pb23); \
      Pd[12] = make_float2(pb24, pb25); Pd[13] = make_float2(pb26, pb27); \
      Pd[14] = make_float2(pb28, pb29); Pd[15] = make_float2(pb30, pb31); \
    } \
    __hip_atomic_store(&flagz[w], cc+1, __ATOMIC_RELEASE, \
                       __HIP_MEMORY_SCOPE_WORKGROUP); \
  } }

__global__ __launch_bounds__(256, 1)
void sdtw_kernel(const float* __restrict__ input,
                 const float* __restrict__ target,
                 float* __restrict__ out) {
  const int b = blockIdx.x;
  const int t = threadIdx.x;          // 0..255; rows 2t, 2t+1
  const int w = t >> 6;               // wave 0..3
  const int lane = t & 63;

  __shared__ __align__(8) float dxe[1576];     // dx[j] at dxe[514+j]; zero pad
  __shared__ __align__(16) float Mbx[4][1040]; // Mbx[w][d] = boundary diag d
  __shared__ int flagz[4];

  const float* __restrict__ inp = input + b * 512;
  const float* __restrict__ tgt = target + b * 512;

  for (int idx = t; idx < 1576; idx += 256) {
    float v = 0.0f;
    if (idx >= 514 && idx <= 1024) v = inp[idx - 513] - inp[idx - 514];
    dxe[idx] = v;
  }
  for (int k2 = t; k2 < 4 * 1040; k2 += 256) (&Mbx[0][0])[k2] = INF_F;
  if (t < 4) flagz[t] = 0;

  // dy for the two owned rows
  float dy_lo = (t >= 1) ? (tgt[2*t] - tgt[2*t - 1]) : 0.0f;  // row 2t
  float dy_hi = tgt[2*t + 1] - tgt[2*t];                      // row 2t+1

  // state at chunk 0 (d starts at 2): diag-1 values all INF; diag-0: R[0][0]=0
  float r1_lo = INF_F, r1_hi = INF_F;
  float r2_lo = (t == 0) ? 0.0f : INF_F;
  float SH2   = INF_F;                // neighbor hi @ diag 0 (none exists)

  v4f q0 = {INF_F, INF_F, INF_F, INF_F};
  v4f q1 = q0, q2 = q0, q3 = q0, q4 = q0, q5 = q0, q6 = q0, q7 = q0;
  float m32v = INF_F;
  float pb0,  pb1,  pb2,  pb3,  pb4,  pb5,  pb6,  pb7;
  float pb8,  pb9,  pb10, pb11, pb12, pb13, pb14, pb15;
  float pb16, pb17, pb18, pb19, pb20, pb21, pb22, pb23;
  float pb24, pb25, pb26, pb27, pb28, pb29, pb30, pb31;
  float xa0,xa1,xa2,xa3,xa4,xa5,xa6,xa7,xa8,xa9,xa10,xa11,xa12,xa13,xa14,xa15;
  float xa16,xa17,xa18,xa19,xa20,xa21,xa22,xa23,xa24,xa25,xa26,xa27,xa28,xa29;
  float xa30,xa31,xa32,xa33;
  float xb0,xb1,xb2,xb3,xb4,xb5,xb6,xb7,xb8,xb9,xb10,xb11,xb12,xb13,xb14,xb15;
  float xb16,xb17,xb18,xb19,xb20,xb21,xb22,xb23,xb24,xb25,xb26,xb27,xb28,xb29;
  float xb30,xb31,xb32,xb33;

  float ans = INF_F;
  const float2* dxe2 = (const float2*)dxe;

  __syncthreads();                    // staging visible; only barrier

  LOADW(xa, 257 - t);                 // chunk 0 window (logical dx[-2t .. ])

#pragma unroll 1
  for (int c = 0; c < 32; c += 2) {
    CHUNK(c,     xa, xb)
    CHUNK(c + 1, xb, xa)
  }

  if (w == 3 && lane == 63) {
    atomicAdd(out, ans * (1.0f / 64.0f));
  }
}

extern "C" void kernel_launch(void* const* d_in, const int* in_sizes, int n_in,
                              void* d_out, int out_size, void* d_ws, size_t ws_size,
                              hipStream_t stream) {
  const float* input  = (const float*)d_in[0];
  const float* target = (const float*)d_in[1];
  float* out = (float*)d_out;

  hipMemsetAsync(out, 0, sizeof(float), stream);
  sdtw_kernel<<<64, 256, 0, stream>>>(input, target, out);
}